// Round 15
// baseline (160.420 us; speedup 1.0000x reference)
//
#include <hip/hip_runtime.h>

typedef __attribute__((ext_vector_type(8))) short short8;
typedef __attribute__((ext_vector_type(4))) float f32x4;

#define B_DIM 2048
#define P_DIM 2048
#define R_DIM 4096
#define H_DIM 6
#define M_DIM 256
#define A_DIM 256
#define OUT_STRIDE 2560   // P + M + A
#define NB 4              // batch rows per main_fused block (packed 4xbf16)

// exp2-form constants: e = exp2(-C1*val);  g = -K2*log2(sum e)*gate
#define C1 14.426950408889634f   // 10/ln2 = 1/(tau*ln2)
#define K2 0.06931471805599453f  // ln2/10
#define C2 7.213475204444817f    // 5/ln2
#define K3 0.13862943611198906f  // ln2/5

static __device__ __forceinline__ float fexp2(float x) { return __builtin_amdgcn_exp2f(x); }
static __device__ __forceinline__ float flog2(float x) { return __builtin_amdgcn_logf(x); }

static __device__ __forceinline__ unsigned short f2bf(float f) {
    unsigned u = __builtin_bit_cast(unsigned, f);
    u += 0x7fffu + ((u >> 16) & 1u);          // round-to-nearest-even
    return (unsigned short)(u >> 16);
}
static __device__ __forceinline__ float bf2f_lo(unsigned u) {   // low bf16 -> f32
    return __builtin_bit_cast(float, u << 16);
}
static __device__ __forceinline__ float bf2f_hi(unsigned u) {   // high bf16 -> f32
    return __builtin_bit_cast(float, u & 0xFFFF0000u);
}
static __device__ __forceinline__ unsigned short f2h(float f) {
    return __builtin_bit_cast(unsigned short, (_Float16)f);
}
static __device__ __forceinline__ float h2f(unsigned short u) {
    return (float)__builtin_bit_cast(_Float16, u);
}

// ---------------------------------------------------------------------------
// prep_meta: pack rule metadata (6x u16 idx, masked -> sentinel 2048; u16
// head, 0xFFFF if >=256). Also zeroes the split-K region counters.
// ---------------------------------------------------------------------------
__global__ __launch_bounds__(256) void prep_meta(
    const int* __restrict__ bidx, const float* __restrict__ bmask,
    const int* __restrict__ hidx, uint4* __restrict__ meta,
    unsigned* __restrict__ cnt)
{
    if (blockIdx.x == 0 && threadIdx.x < 128) cnt[threadIdx.x] = 0;
    const int r = blockIdx.x * 256 + threadIdx.x;   // 4096
    const int* bi = bidx + r * H_DIM;
    const float* bm = bmask + r * H_DIM;
    unsigned s[H_DIM];
    #pragma unroll
    for (int h = 0; h < H_DIM; h++)
        s[h] = (bm[h] > 0.0f) ? (unsigned)bi[h] : 2048u;
    const int hh = hidx[r];
    unsigned sh = (hh < M_DIM) ? (unsigned)hh : 0xFFFFu;
    uint4 m;
    m.x = s[0] | (s[1] << 16);
    m.y = s[2] | (s[3] << 16);
    m.z = s[4] | (s[5] << 16);
    m.w = sh;
    meta[r] = m;
}

// ---------------------------------------------------------------------------
// Main fused kernel (r14 structure, unchanged): NB=4 rows/block, 1024 thr,
// grid 512 = 2 blocks/CU. vrowu4[p] = 4x bf16 e = exp2(-C1*val).
// ---------------------------------------------------------------------------
__global__ __launch_bounds__(1024, 8) void main_fused(
    const float* __restrict__ M_minus, const float* __restrict__ amask,
    const float* __restrict__ gate,    const uint4* __restrict__ meta,
    const float* __restrict__ GA, const float* __restrict__ GB,
    const float* __restrict__ isM, const float* __restrict__ isA,
    const float* __restrict__ w,
    unsigned short* __restrict__ GAT, unsigned short* __restrict__ GBT,
    unsigned short* __restrict__ wb,
    unsigned short* __restrict__ g_bf, unsigned short* __restrict__ mclip_bf,
    float* __restrict__ outp)
{
    __shared__ __align__(16) union SM {
        struct {
            uint2 vrowu4[2052];          // [p] = 4x bf16 e-values
            float shead[NB][M_DIM];
        } mf;
        float prep[4][32][33];
    } sm;
    const int bid = blockIdx.x;
    const int tid = threadIdx.x;
    const int b0 = bid * NB;

    // ---- fused prep: 512 blocks x 4 transpose units (=2048); w on 0..63 ----
    {
        const int s = tid >> 8, lt = tid & 255;
        const int u = bid * 4 + s;                 // 0..2047
        const int tx = lt & 31, ty = lt >> 5;
        const int which = u >> 10;
        const int rem = u & 1023;
        const float* src = which ? GB : GA;
        const float* scv = which ? isA : isM;
        const int r0 = (rem >> 3) * 32;            // K (=R) dim
        const int n0 = (rem & 7) * 32;             // N (=256) dim
        #pragma unroll
        for (int q = 0; q < 4; q++) {
            int rr = ty + q * 8;
            sm.prep[s][rr][tx] = scv[r0 + rr] * src[(size_t)(r0 + rr) * 256 + n0 + tx];
        }
        __syncthreads();
        unsigned short* dst = which ? GBT : GAT;
        #pragma unroll
        for (int q = 0; q < 4; q++) {
            int nn = ty + q * 8;
            dst[(size_t)(n0 + nn) * R_DIM + r0 + tx] = f2bf(sm.prep[s][tx][nn]);
        }
        if (bid < 64) {
            const int i = bid * 1024 + tid;        // 65536 total
            wb[i] = f2bf(w[i]);
        }
        __syncthreads();   // protect LDS reuse by mf phases
    }

    // ---- mf init ----
    if (tid < NB * M_DIM) sm.mf.shead[tid >> 8][tid & 255] = 0.0f;
    if (tid == 0) sm.mf.vrowu4[2048] = make_uint2(0u, 0u);   // sentinel e=0

    // phase 1: each thread builds p0=2t, p0+1 for all 4 rows (e packed bf16)
    {
        const int p0 = tid * 2;
        float2 a[NB];
        #pragma unroll
        for (int r = 0; r < NB; r++)
            a[r] = *(const float2*)(amask + (size_t)(b0 + r) * P_DIM + p0);
        if (tid < M_DIM / 2) {
            #pragma unroll
            for (int r = 0; r < NB; r++) {
                float2 m = *(const float2*)(M_minus + (size_t)(b0 + r) * M_DIM + p0);
                float mc0 = fminf(fmaxf(m.x, 0.0f), 1.0f);
                float mc1 = fminf(fmaxf(m.y, 0.0f), 1.0f);
                ushort2 wv; wv.x = f2bf(mc0); wv.y = f2bf(mc1);
                *(ushort2*)(mclip_bf + (size_t)(b0 + r) * M_DIM + p0) = wv;
                a[r].x = fmaxf(mc0, a[r].x);
                a[r].y = fmaxf(mc1, a[r].y);
            }
        }
        float e0[NB], e1[NB];
        #pragma unroll
        for (int r = 0; r < NB; r++) {
            e0[r] = fexp2(-C1 * a[r].x);
            e1[r] = fexp2(-C1 * a[r].y);
        }
        uint4 pk;
        pk.x = (unsigned)f2bf(e0[0]) | ((unsigned)f2bf(e0[1]) << 16);
        pk.y = (unsigned)f2bf(e0[2]) | ((unsigned)f2bf(e0[3]) << 16);
        pk.z = (unsigned)f2bf(e1[0]) | ((unsigned)f2bf(e1[1]) << 16);
        pk.w = (unsigned)f2bf(e1[2]) | ((unsigned)f2bf(e1[3]) << 16);
        *(uint4*)&sm.mf.vrowu4[p0] = pk;
    }
    __syncthreads();

    // phase 2: rules, 4 iterations, meta prefetch distance 1
    uint4 mc = meta[tid];
    #pragma unroll
    for (int it = 0; it < R_DIM / 1024; it++) {
        const int rr = tid + it * 1024;
        uint4 mn = mc;
        if (it < R_DIM / 1024 - 1) mn = meta[rr + 1024];
        float gv[NB];
        #pragma unroll
        for (int r = 0; r < NB; r++)
            gv[r] = gate[(size_t)(b0 + r) * R_DIM + rr];
        const int i0 = mc.x & 0xFFFF, i1 = mc.x >> 16;
        const int i2 = mc.y & 0xFFFF, i3 = mc.y >> 16;
        const int i4 = mc.z & 0xFFFF, i5 = mc.z >> 16;
        const int hh = mc.w & 0xFFFF;
        uint2 u0 = sm.mf.vrowu4[i0], u1 = sm.mf.vrowu4[i1], u2 = sm.mf.vrowu4[i2];
        uint2 u3 = sm.mf.vrowu4[i3], u4 = sm.mf.vrowu4[i4], u5 = sm.mf.vrowu4[i5];

        float s0 = bf2f_lo(u0.x) + bf2f_lo(u1.x) + bf2f_lo(u2.x)
                 + bf2f_lo(u3.x) + bf2f_lo(u4.x) + bf2f_lo(u5.x);
        float s1 = bf2f_hi(u0.x) + bf2f_hi(u1.x) + bf2f_hi(u2.x)
                 + bf2f_hi(u3.x) + bf2f_hi(u4.x) + bf2f_hi(u5.x);
        float s2 = bf2f_lo(u0.y) + bf2f_lo(u1.y) + bf2f_lo(u2.y)
                 + bf2f_lo(u3.y) + bf2f_lo(u4.y) + bf2f_lo(u5.y);
        float s3 = bf2f_hi(u0.y) + bf2f_hi(u1.y) + bf2f_hi(u2.y)
                 + bf2f_hi(u3.y) + bf2f_hi(u4.y) + bf2f_hi(u5.y);
        float gg0 = flog2(s0) * (-K2 * gv[0]);
        float gg1 = flog2(s1) * (-K2 * gv[1]);
        float gg2 = flog2(s2) * (-K2 * gv[2]);
        float gg3 = flog2(s3) * (-K2 * gv[3]);
        g_bf[(size_t)b0 * R_DIM + rr]       = f2bf(gg0);
        g_bf[(size_t)(b0 + 1) * R_DIM + rr] = f2bf(gg1);
        g_bf[(size_t)(b0 + 2) * R_DIM + rr] = f2bf(gg2);
        g_bf[(size_t)(b0 + 3) * R_DIM + rr] = f2bf(gg3);
        if (hh < M_DIM) {
            atomicAdd(&sm.mf.shead[0][hh], fexp2(gg0 * C2));
            atomicAdd(&sm.mf.shead[1][hh], fexp2(gg1 * C2));
            atomicAdd(&sm.mf.shead[2][hh], fexp2(gg2 * C2));
            atomicAdd(&sm.mf.shead[3][hh], fexp2(gg3 * C2));
        }
        mc = mn;
    }
    __syncthreads();

    // phase 3: val_new columns of out (val = -K2*log2(e))
    {
        const int p0 = tid * 2;
        uint4 uu = *(const uint4*)&sm.mf.vrowu4[p0];
        float v[NB][2];
        v[0][0] = -K2 * flog2(bf2f_lo(uu.x)); v[1][0] = -K2 * flog2(bf2f_hi(uu.x));
        v[2][0] = -K2 * flog2(bf2f_lo(uu.y)); v[3][0] = -K2 * flog2(bf2f_hi(uu.y));
        v[0][1] = -K2 * flog2(bf2f_lo(uu.z)); v[1][1] = -K2 * flog2(bf2f_hi(uu.z));
        v[2][1] = -K2 * flog2(bf2f_lo(uu.w)); v[3][1] = -K2 * flog2(bf2f_hi(uu.w));
        if (tid < M_DIM / 2) {
            #pragma unroll
            for (int r = 0; r < NB; r++) {
                float sa = sm.mf.shead[r][p0], sb = sm.mf.shead[r][p0 + 1];
                if (sa > 0.0f) v[r][0] = fmaxf(v[r][0], K3 * flog2(sa));
                if (sb > 0.0f) v[r][1] = fmaxf(v[r][1], K3 * flog2(sb));
            }
        }
        #pragma unroll
        for (int r = 0; r < NB; r++)
            *(float2*)(outp + (size_t)(b0 + r) * OUT_STRIDE + p0) =
                make_float2(v[r][0], v[r][1]);
    }
}

// ---------------------------------------------------------------------------
// global_load_lds 16B staging, XOR-swizzled source, linear LDS dest. BK=128.
// ---------------------------------------------------------------------------
__device__ __forceinline__ void stage16(unsigned short* lds,
                                        const unsigned short* gsrc,
                                        int K, int c)
{
    const int row = c >> 4, slot = c & 15;
    const int k8 = slot ^ (row & 15);      // logical 16B chunk at this slot
    __builtin_amdgcn_global_load_lds(
        (const __attribute__((address_space(1))) void*)(gsrc + (size_t)row * K + k8 * 8),
        (__attribute__((address_space(3))) void*)(lds + c * 8), 16, 0, 0);
}

// ---------------------------------------------------------------------------
// Region reducer: sum 4 main f16 partials -> relu; for n>=256 regions also
// add softplus(b + 2-slice lam sum). Region = 128 rows x 64 cols.
// Deterministic: fixed z-order summation regardless of which block runs it.
// ---------------------------------------------------------------------------
__device__ __forceinline__ void reduce_region(
    int mi, int ni,
    const unsigned short* __restrict__ mainp,
    const unsigned short* __restrict__ lampart,
    const float* __restrict__ bvec, float* __restrict__ outp, int tid)
{
    const size_t zs = (size_t)B_DIM * 128;       // ushort4 units per z slice
    #pragma unroll
    for (int itr = 0; itr < 8; itr++) {
        const int u = itr * 256 + tid;           // over 128x16 ushort4 units
        const int ml = u >> 4, c4 = u & 15;
        const int gm = mi * 128 + ml;
        const int gn = ni * 64 + c4 * 4;
        const size_t mb = (size_t)gm * 128 + (gn >> 2);
        float sx = 0.0f, sy = 0.0f, sz = 0.0f, sw = 0.0f;
        #pragma unroll
        for (int z = 0; z < 4; z++) {
            ushort4 t = ((const ushort4*)mainp)[mb + z * zs];
            sx += h2f(t.x); sy += h2f(t.y); sz += h2f(t.z); sw += h2f(t.w);
        }
        sx = fmaxf(sx, 0.0f); sy = fmaxf(sy, 0.0f);
        sz = fmaxf(sz, 0.0f); sw = fmaxf(sw, 0.0f);
        if (ni >= 4) {
            const int na = gn - 256;
            const size_t lb = (size_t)gm * 64 + (na >> 2);
            const size_t ls = (size_t)B_DIM * 64;
            ushort4 u0 = ((const ushort4*)lampart)[lb];
            ushort4 u1 = ((const ushort4*)lampart)[lb + ls];
            float4 bb = ((const float4*)bvec)[na >> 2];
            float x0 = bb.x + h2f(u0.x) + h2f(u1.x);
            float x1 = bb.y + h2f(u0.y) + h2f(u1.y);
            float x2 = bb.z + h2f(u0.z) + h2f(u1.z);
            float x3 = bb.w + h2f(u0.w) + h2f(u1.w);
            sx += (x0 > 20.0f) ? x0 : log1pf(__expf(x0));
            sy += (x1 > 20.0f) ? x1 : log1pf(__expf(x1));
            sz += (x2 > 20.0f) ? x2 : log1pf(__expf(x2));
            sw += (x3 > 20.0f) ? x3 : log1pf(__expf(x3));
        }
        float4 s; s.x = sx; s.y = sy; s.z = sz; s.w = sw;
        ((float4*)(outp + (size_t)gm * OUT_STRIDE + 2048))[gn >> 2] = s;
    }
}

// ---------------------------------------------------------------------------
// Merged GEMM + fused epilogue, 768 blocks x 256 threads, f16 partials:
//   bid < 512 : main [S|lam_logic]: BM=128,BN=64,BK=128, K=4096, z=4,
//               logical (16 m, 8 n, 4 z), XCD-chunk swizzled.
//   bid >= 512: lam_ment: BM=64,BN=64,BK=128, K=256, z=2.
// After partial store: __threadfence + device atomicAdd on region counter;
// the completing block (4 contributors for n<256 regions, 8 for n>=256)
// performs the relu/softplus reduction directly to out.
// ---------------------------------------------------------------------------
__global__ __launch_bounds__(256) void gemm_all(
    const unsigned short* __restrict__ g_bf,
    const unsigned short* __restrict__ GAT,
    const unsigned short* __restrict__ mclip,
    const unsigned short* __restrict__ w_bf,
    unsigned short* __restrict__ mainp, unsigned short* __restrict__ lamp,
    const float* __restrict__ bvec, float* __restrict__ outp,
    unsigned* __restrict__ cnt)
{
    __shared__ __align__(16) unsigned short Alds[128 * 128];
    __shared__ __align__(16) unsigned short Blds[64 * 128];
    const int bid = blockIdx.x;
    const int tid = threadIdx.x;
    const int lane = tid & 63, wid = tid >> 6;
    const int wr = wid >> 1, wc = wid & 1;

    int mi, ni;   // output region coordinates (128-row x 64-col)

    if (bid < 512) {
        // ---- main path: logical (16 m, 8 n, 4 z), XCD-chunk swizzled ----
        const int l = (bid & 7) * 64 + (bid >> 3);
        const int m0 = (l & 15) * 128;
        const int n0 = ((l >> 4) & 7) * 64;
        const int z  = l >> 7;
        const int K = R_DIM, Kc = R_DIM / 4, k0 = z * Kc, NS = 512;
        unsigned short* part = mainp + (size_t)z * B_DIM * NS;
        f32x4 acc[4][2] = {};

        for (int kt = 0; kt < Kc; kt += 128) {
            const unsigned short* Ab = g_bf + (size_t)m0 * K + k0 + kt;
            const unsigned short* Bb = GAT  + (size_t)n0 * K + k0 + kt;
            #pragma unroll
            for (int q = 0; q < 8; q++) stage16(Alds, Ab, K, tid + q * 256);
            #pragma unroll
            for (int q = 0; q < 4; q++) stage16(Blds, Bb, K, tid + q * 256);
            __syncthreads();
            #pragma unroll
            for (int ks = 0; ks < 4; ks++) {
                const int k8 = ks * 4 + (lane >> 4);
                const int ra = wr * 64 + (lane & 15);
                const int rb = wc * 32 + (lane & 15);
                const int sa = (k8 ^ (ra & 15)) << 3;
                const int sb = (k8 ^ (rb & 15)) << 3;
                short8 a0 = *(const short8*)&Alds[(ra)      * 128 + sa];
                short8 a1 = *(const short8*)&Alds[(ra + 16) * 128 + sa];
                short8 a2 = *(const short8*)&Alds[(ra + 32) * 128 + sa];
                short8 a3 = *(const short8*)&Alds[(ra + 48) * 128 + sa];
                short8 b0 = *(const short8*)&Blds[(rb)      * 128 + sb];
                short8 b1 = *(const short8*)&Blds[(rb + 16) * 128 + sb];
                acc[0][0] = __builtin_amdgcn_mfma_f32_16x16x32_bf16(a0, b0, acc[0][0], 0, 0, 0);
                acc[0][1] = __builtin_amdgcn_mfma_f32_16x16x32_bf16(a0, b1, acc[0][1], 0, 0, 0);
                acc[1][0] = __builtin_amdgcn_mfma_f32_16x16x32_bf16(a1, b0, acc[1][0], 0, 0, 0);
                acc[1][1] = __builtin_amdgcn_mfma_f32_16x16x32_bf16(a1, b1, acc[1][1], 0, 0, 0);
                acc[2][0] = __builtin_amdgcn_mfma_f32_16x16x32_bf16(a2, b0, acc[2][0], 0, 0, 0);
                acc[2][1] = __builtin_amdgcn_mfma_f32_16x16x32_bf16(a2, b1, acc[2][1], 0, 0, 0);
                acc[3][0] = __builtin_amdgcn_mfma_f32_16x16x32_bf16(a3, b0, acc[3][0], 0, 0, 0);
                acc[3][1] = __builtin_amdgcn_mfma_f32_16x16x32_bf16(a3, b1, acc[3][1], 0, 0, 0);
            }
            __syncthreads();
        }
        const int rbase = (lane >> 4) * 4;
        const int cbase = lane & 15;
        #pragma unroll
        for (int i = 0; i < 4; i++) {
            #pragma unroll
            for (int j = 0; j < 2; j++) {
                const int gn = n0 + wc * 32 + j * 16 + cbase;
                #pragma unroll
                for (int q = 0; q < 4; q++) {
                    const int gm = m0 + wr * 64 + i * 16 + rbase + q;
                    part[(size_t)gm * NS + gn] = f2h(acc[i][j][q]);
                }
            }
        }
        mi = m0 >> 7; ni = n0 >> 6;
    } else {
        // ---- lam path: grid (32 m, 4 n, 2 z) ----
        const int l = bid - 512;
        const int m0 = (l & 31) * 64;
        const int n0 = ((l >> 5) & 3) * 64;
        const int z  = l >> 7;
        const int K = M_DIM, Kc = M_DIM / 2, k0 = z * Kc, NS = A_DIM;
        unsigned short* part = lamp + (size_t)z * B_DIM * NS;
        f32x4 acc[2][2] = {};

        // Kc = 128 -> single K-tile
        const unsigned short* Ab = mclip + (size_t)m0 * K + k0;
        const unsigned short* Bb = w_bf  + (size_t)n0 * K + k0;
        #pragma unroll
        for (int q = 0; q < 4; q++) {
            stage16(Alds, Ab, K, tid + q * 256);
            stage16(Blds, Bb, K, tid + q * 256);
        }
        __syncthreads();
        #pragma unroll
        for (int ks = 0; ks < 4; ks++) {
            const int k8 = ks * 4 + (lane >> 4);
            const int r0a = wr * 32 + (lane & 15);
            const int r0b = wc * 32 + (lane & 15);
            const int sa = (k8 ^ (r0a & 15)) << 3;
            const int sb = (k8 ^ (r0b & 15)) << 3;
            short8 a0 = *(const short8*)&Alds[(r0a)      * 128 + sa];
            short8 a1 = *(const short8*)&Alds[(r0a + 16) * 128 + sa];
            short8 b0 = *(const short8*)&Blds[(r0b)      * 128 + sb];
            short8 b1 = *(const short8*)&Blds[(r0b + 16) * 128 + sb];
            acc[0][0] = __builtin_amdgcn_mfma_f32_16x16x32_bf16(a0, b0, acc[0][0], 0, 0, 0);
            acc[0][1] = __builtin_amdgcn_mfma_f32_16x16x32_bf16(a0, b1, acc[0][1], 0, 0, 0);
            acc[1][0] = __builtin_amdgcn_mfma_f32_16x16x32_bf16(a1, b0, acc[1][0], 0, 0, 0);
            acc[1][1] = __builtin_amdgcn_mfma_f32_16x16x32_bf16(a1, b1, acc[1][1], 0, 0, 0);
        }
        const int rbase = (lane >> 4) * 4;
        const int cbase = lane & 15;
        #pragma unroll
        for (int i = 0; i < 2; i++) {
            #pragma unroll
            for (int j = 0; j < 2; j++) {
                const int gn = n0 + wc * 32 + j * 16 + cbase;
                #pragma unroll
                for (int q = 0; q < 4; q++) {
                    const int gm = m0 + wr * 32 + i * 16 + rbase + q;
                    part[(size_t)gm * NS + gn] = f2h(acc[i][j][q]);
                }
            }
        }
        mi = (l & 31) >> 1; ni = 4 + ((l >> 5) & 3);
    }

    // ---- fused split-K epilogue: last contributor of region reduces ----
    const int region = mi * 8 + ni;
    const unsigned target = (ni >= 4) ? 8u : 4u;
    __syncthreads();                 // all partial stores issued
    __threadfence();                 // device-scope release (cross-XCD)
    __shared__ unsigned old_sm;
    if (tid == 0) old_sm = atomicAdd(&cnt[region], 1u);
    __syncthreads();
    if (old_sm == target - 1) {
        __threadfence();             // device-scope acquire
        reduce_region(mi, ni, mainp, lamp, bvec, outp, tid);
    }
}

// ---------------------------------------------------------------------------
extern "C" void kernel_launch(void* const* d_in, const int* in_sizes, int n_in,
                              void* d_out, int out_size, void* d_ws, size_t ws_size,
                              hipStream_t stream)
{
    const float* M_minus = (const float*)d_in[0];
    const float* amask   = (const float*)d_in[1];
    const float* gate    = (const float*)d_in[2];
    const float* bmask   = (const float*)d_in[3];
    const float* isM     = (const float*)d_in[4];
    const float* isA     = (const float*)d_in[5];
    const float* GA      = (const float*)d_in[6];
    const float* GB      = (const float*)d_in[7];
    const float* bvec    = (const float*)d_in[8];
    const float* w       = (const float*)d_in[9];
    const int*   bidx    = (const int*)d_in[10];
    const int*   hidx    = (const int*)d_in[11];
    float* outp = (float*)d_out;

    char* ws = (char*)d_ws;
    unsigned short* g_bf   = (unsigned short*)(ws + 0);          // 16 MiB
    unsigned short* GAT    = (unsigned short*)(ws + (16u<<20));  // 2 MiB
    unsigned short* GBT    = (unsigned short*)(ws + (18u<<20));  // 2 MiB (contiguous after GAT)
    unsigned short* w_bf   = (unsigned short*)(ws + (20u<<20));  // 128 KiB
    uint4*          meta   = (uint4*)(ws + (20u<<20) + (256u<<10)); // 64 KiB
    unsigned short* mclip  = (unsigned short*)(ws + (21u<<20));  // 1 MiB
    unsigned short* mainp  = (unsigned short*)(ws + (22u<<20));  // 4 x 2 MiB (f16)
    unsigned short* lamp   = (unsigned short*)(ws + (38u<<20));  // 2 x 1 MiB (f16)
    unsigned*       cnt    = (unsigned*)(ws + (41u<<20));        // 128 u32

    prep_meta<<<dim3(R_DIM / 256), dim3(256), 0, stream>>>(
        bidx, bmask, hidx, meta, cnt);
    main_fused<<<dim3(B_DIM / NB), dim3(1024), 0, stream>>>(
        M_minus, amask, gate, meta, GA, GB, isM, isA, w,
        GAT, GBT, w_bf, g_bf, mclip, outp);
    gemm_all<<<dim3(768), dim3(256), 0, stream>>>(
        g_bf, GAT, mclip, w_bf, mainp, lamp, bvec, outp, cnt);
}

// Round 16
// 47.943 us; speedup vs baseline: 3.3461x; 3.3461x over previous
//
#include <hip/hip_runtime.h>

typedef __attribute__((ext_vector_type(8))) short short8;
typedef __attribute__((ext_vector_type(4))) float f32x4;

#define B_DIM 2048
#define P_DIM 2048
#define R_DIM 4096
#define H_DIM 6
#define M_DIM 256
#define A_DIM 256
#define OUT_STRIDE 2560   // P + M + A
#define NB 4              // batch rows per main_fused block (packed 4xbf16)

// exp2-form constants: e = exp2(-C1*val);  g = -K2*log2(sum e)*gate
#define C1 14.426950408889634f   // 10/ln2 = 1/(tau*ln2)
#define K2 0.06931471805599453f  // ln2/10
#define C2 7.213475204444817f    // 5/ln2
#define K3 0.13862943611198906f  // ln2/5

static __device__ __forceinline__ float fexp2(float x) { return __builtin_amdgcn_exp2f(x); }
static __device__ __forceinline__ float flog2(float x) { return __builtin_amdgcn_logf(x); }

static __device__ __forceinline__ unsigned short f2bf(float f) {
    unsigned u = __builtin_bit_cast(unsigned, f);
    u += 0x7fffu + ((u >> 16) & 1u);          // round-to-nearest-even
    return (unsigned short)(u >> 16);
}
static __device__ __forceinline__ float bf2f_lo(unsigned u) {   // low bf16 -> f32
    return __builtin_bit_cast(float, u << 16);
}
static __device__ __forceinline__ float bf2f_hi(unsigned u) {   // high bf16 -> f32
    return __builtin_bit_cast(float, u & 0xFFFF0000u);
}
static __device__ __forceinline__ unsigned short f2h(float f) {
    return __builtin_bit_cast(unsigned short, (_Float16)f);
}
static __device__ __forceinline__ float h2f(unsigned short u) {
    return (float)__builtin_bit_cast(_Float16, u);
}

// ---------------------------------------------------------------------------
// prep_meta: pack rule metadata (6x u16 idx, masked -> sentinel 2048; u16
// head, 0xFFFF if >=256). Must precede main_fused (which consumes meta).
// ---------------------------------------------------------------------------
__global__ __launch_bounds__(256) void prep_meta(
    const int* __restrict__ bidx, const float* __restrict__ bmask,
    const int* __restrict__ hidx, uint4* __restrict__ meta)
{
    const int r = blockIdx.x * 256 + threadIdx.x;   // 4096
    const int* bi = bidx + r * H_DIM;
    const float* bm = bmask + r * H_DIM;
    unsigned s[H_DIM];
    #pragma unroll
    for (int h = 0; h < H_DIM; h++)
        s[h] = (bm[h] > 0.0f) ? (unsigned)bi[h] : 2048u;
    const int hh = hidx[r];
    unsigned sh = (hh < M_DIM) ? (unsigned)hh : 0xFFFFu;
    uint4 m;
    m.x = s[0] | (s[1] << 16);
    m.y = s[2] | (s[3] << 16);
    m.z = s[4] | (s[5] << 16);
    m.w = sh;
    meta[r] = m;
}

// ---------------------------------------------------------------------------
// Main fused kernel: NB=4 rows/block, 1024 threads, grid 512 = exactly
// 2 blocks/CU resident (32 waves/CU).
// vrowu4[p] = uint2 of 4x bf16 e-values, e = exp2(-C1*val): per-instance
// softmin needs only SUM of gathered e. Masked sentinel stores e=0.
// s>0 guaranteed (body_mask[:,0]==1).
// ---------------------------------------------------------------------------
__global__ __launch_bounds__(1024, 8) void main_fused(
    const float* __restrict__ M_minus, const float* __restrict__ amask,
    const float* __restrict__ gate,    const uint4* __restrict__ meta,
    const float* __restrict__ GA, const float* __restrict__ GB,
    const float* __restrict__ isM, const float* __restrict__ isA,
    const float* __restrict__ w,
    unsigned short* __restrict__ GAT, unsigned short* __restrict__ GBT,
    unsigned short* __restrict__ wb,
    unsigned short* __restrict__ g_bf, unsigned short* __restrict__ mclip_bf,
    float* __restrict__ outp)
{
    __shared__ __align__(16) union SM {
        struct {
            uint2 vrowu4[2052];          // [p] = 4x bf16 e-values
            float shead[NB][M_DIM];
        } mf;
        float prep[4][32][33];
    } sm;
    const int bid = blockIdx.x;
    const int tid = threadIdx.x;
    const int b0 = bid * NB;

    // ---- fused prep: 512 blocks x 4 transpose units (=2048); w on 0..63 ----
    {
        const int s = tid >> 8, lt = tid & 255;
        const int u = bid * 4 + s;                 // 0..2047
        const int tx = lt & 31, ty = lt >> 5;
        const int which = u >> 10;
        const int rem = u & 1023;
        const float* src = which ? GB : GA;
        const float* scv = which ? isA : isM;
        const int r0 = (rem >> 3) * 32;            // K (=R) dim
        const int n0 = (rem & 7) * 32;             // N (=256) dim
        #pragma unroll
        for (int q = 0; q < 4; q++) {
            int rr = ty + q * 8;
            sm.prep[s][rr][tx] = scv[r0 + rr] * src[(size_t)(r0 + rr) * 256 + n0 + tx];
        }
        __syncthreads();
        unsigned short* dst = which ? GBT : GAT;
        #pragma unroll
        for (int q = 0; q < 4; q++) {
            int nn = ty + q * 8;
            dst[(size_t)(n0 + nn) * R_DIM + r0 + tx] = f2bf(sm.prep[s][tx][nn]);
        }
        if (bid < 64) {
            const int i = bid * 1024 + tid;        // 65536 total
            wb[i] = f2bf(w[i]);
        }
        __syncthreads();   // protect LDS reuse by mf phases
    }

    // ---- mf init ----
    if (tid < NB * M_DIM) sm.mf.shead[tid >> 8][tid & 255] = 0.0f;
    if (tid == 0) sm.mf.vrowu4[2048] = make_uint2(0u, 0u);   // sentinel e=0

    // phase 1: each thread builds p0=2t, p0+1 for all 4 rows (e packed bf16)
    {
        const int p0 = tid * 2;
        float2 a[NB];
        #pragma unroll
        for (int r = 0; r < NB; r++)
            a[r] = *(const float2*)(amask + (size_t)(b0 + r) * P_DIM + p0);
        if (tid < M_DIM / 2) {
            #pragma unroll
            for (int r = 0; r < NB; r++) {
                float2 m = *(const float2*)(M_minus + (size_t)(b0 + r) * M_DIM + p0);
                float mc0 = fminf(fmaxf(m.x, 0.0f), 1.0f);
                float mc1 = fminf(fmaxf(m.y, 0.0f), 1.0f);
                ushort2 wv; wv.x = f2bf(mc0); wv.y = f2bf(mc1);
                *(ushort2*)(mclip_bf + (size_t)(b0 + r) * M_DIM + p0) = wv;
                a[r].x = fmaxf(mc0, a[r].x);
                a[r].y = fmaxf(mc1, a[r].y);
            }
        }
        float e0[NB], e1[NB];
        #pragma unroll
        for (int r = 0; r < NB; r++) {
            e0[r] = fexp2(-C1 * a[r].x);
            e1[r] = fexp2(-C1 * a[r].y);
        }
        uint4 pk;
        pk.x = (unsigned)f2bf(e0[0]) | ((unsigned)f2bf(e0[1]) << 16);
        pk.y = (unsigned)f2bf(e0[2]) | ((unsigned)f2bf(e0[3]) << 16);
        pk.z = (unsigned)f2bf(e1[0]) | ((unsigned)f2bf(e1[1]) << 16);
        pk.w = (unsigned)f2bf(e1[2]) | ((unsigned)f2bf(e1[3]) << 16);
        *(uint4*)&sm.mf.vrowu4[p0] = pk;
    }
    __syncthreads();

    // phase 2: rules, 4 iterations, meta prefetch distance 1,
    // 6 x ds_read_b64 gathers each serving 4 rows; s = sum of gathered e
    uint4 mc = meta[tid];
    #pragma unroll
    for (int it = 0; it < R_DIM / 1024; it++) {
        const int rr = tid + it * 1024;
        uint4 mn = mc;
        if (it < R_DIM / 1024 - 1) mn = meta[rr + 1024];
        float gv[NB];
        #pragma unroll
        for (int r = 0; r < NB; r++)
            gv[r] = gate[(size_t)(b0 + r) * R_DIM + rr];
        const int i0 = mc.x & 0xFFFF, i1 = mc.x >> 16;
        const int i2 = mc.y & 0xFFFF, i3 = mc.y >> 16;
        const int i4 = mc.z & 0xFFFF, i5 = mc.z >> 16;
        const int hh = mc.w & 0xFFFF;
        uint2 u0 = sm.mf.vrowu4[i0], u1 = sm.mf.vrowu4[i1], u2 = sm.mf.vrowu4[i2];
        uint2 u3 = sm.mf.vrowu4[i3], u4 = sm.mf.vrowu4[i4], u5 = sm.mf.vrowu4[i5];

        float s0 = bf2f_lo(u0.x) + bf2f_lo(u1.x) + bf2f_lo(u2.x)
                 + bf2f_lo(u3.x) + bf2f_lo(u4.x) + bf2f_lo(u5.x);
        float s1 = bf2f_hi(u0.x) + bf2f_hi(u1.x) + bf2f_hi(u2.x)
                 + bf2f_hi(u3.x) + bf2f_hi(u4.x) + bf2f_hi(u5.x);
        float s2 = bf2f_lo(u0.y) + bf2f_lo(u1.y) + bf2f_lo(u2.y)
                 + bf2f_lo(u3.y) + bf2f_lo(u4.y) + bf2f_lo(u5.y);
        float s3 = bf2f_hi(u0.y) + bf2f_hi(u1.y) + bf2f_hi(u2.y)
                 + bf2f_hi(u3.y) + bf2f_hi(u4.y) + bf2f_hi(u5.y);
        float gg0 = flog2(s0) * (-K2 * gv[0]);
        float gg1 = flog2(s1) * (-K2 * gv[1]);
        float gg2 = flog2(s2) * (-K2 * gv[2]);
        float gg3 = flog2(s3) * (-K2 * gv[3]);
        g_bf[(size_t)b0 * R_DIM + rr]       = f2bf(gg0);
        g_bf[(size_t)(b0 + 1) * R_DIM + rr] = f2bf(gg1);
        g_bf[(size_t)(b0 + 2) * R_DIM + rr] = f2bf(gg2);
        g_bf[(size_t)(b0 + 3) * R_DIM + rr] = f2bf(gg3);
        if (hh < M_DIM) {
            atomicAdd(&sm.mf.shead[0][hh], fexp2(gg0 * C2));
            atomicAdd(&sm.mf.shead[1][hh], fexp2(gg1 * C2));
            atomicAdd(&sm.mf.shead[2][hh], fexp2(gg2 * C2));
            atomicAdd(&sm.mf.shead[3][hh], fexp2(gg3 * C2));
        }
        mc = mn;
    }
    __syncthreads();

    // phase 3: val_new columns of out (val = -K2*log2(e))
    {
        const int p0 = tid * 2;
        uint4 uu = *(const uint4*)&sm.mf.vrowu4[p0];
        float v[NB][2];
        v[0][0] = -K2 * flog2(bf2f_lo(uu.x)); v[1][0] = -K2 * flog2(bf2f_hi(uu.x));
        v[2][0] = -K2 * flog2(bf2f_lo(uu.y)); v[3][0] = -K2 * flog2(bf2f_hi(uu.y));
        v[0][1] = -K2 * flog2(bf2f_lo(uu.z)); v[1][1] = -K2 * flog2(bf2f_hi(uu.z));
        v[2][1] = -K2 * flog2(bf2f_lo(uu.w)); v[3][1] = -K2 * flog2(bf2f_hi(uu.w));
        if (tid < M_DIM / 2) {
            #pragma unroll
            for (int r = 0; r < NB; r++) {
                float sa = sm.mf.shead[r][p0], sb = sm.mf.shead[r][p0 + 1];
                if (sa > 0.0f) v[r][0] = fmaxf(v[r][0], K3 * flog2(sa));
                if (sb > 0.0f) v[r][1] = fmaxf(v[r][1], K3 * flog2(sb));
            }
        }
        #pragma unroll
        for (int r = 0; r < NB; r++)
            *(float2*)(outp + (size_t)(b0 + r) * OUT_STRIDE + p0) =
                make_float2(v[r][0], v[r][1]);
    }
}

// ---------------------------------------------------------------------------
// global_load_lds 16B staging, XOR-swizzled source, linear LDS dest. BK=128.
// ---------------------------------------------------------------------------
__device__ __forceinline__ void stage16(unsigned short* lds,
                                        const unsigned short* gsrc,
                                        int K, int c)
{
    const int row = c >> 4, slot = c & 15;
    const int k8 = slot ^ (row & 15);      // logical 16B chunk at this slot
    __builtin_amdgcn_global_load_lds(
        (const __attribute__((address_space(1))) void*)(gsrc + (size_t)row * K + k8 * 8),
        (__attribute__((address_space(3))) void*)(lds + c * 8), 16, 0, 0);
}

// ---------------------------------------------------------------------------
// Merged GEMM kernel, 768 blocks x 256 threads, f16 partials (r9 shape):
//   bid < 512 : main [S|lam_logic]: BM=128,BN=64,BK=128, K=4096, z=4,
//               logical (16 m, 8 n, 4 z), XCD-chunk swizzled.
//   bid >= 512: lam_ment: BM=64,BN=64,BK=128, K=256, z=2.
// ---------------------------------------------------------------------------
__global__ __launch_bounds__(256) void gemm_all(
    const unsigned short* __restrict__ g_bf,
    const unsigned short* __restrict__ GAT,
    const unsigned short* __restrict__ mclip,
    const unsigned short* __restrict__ w_bf,
    unsigned short* __restrict__ mainp, unsigned short* __restrict__ lamp)
{
    __shared__ __align__(16) unsigned short Alds[128 * 128];
    __shared__ __align__(16) unsigned short Blds[64 * 128];
    const int bid = blockIdx.x;
    const int tid = threadIdx.x;
    const int lane = tid & 63, wid = tid >> 6;
    const int wr = wid >> 1, wc = wid & 1;

    if (bid < 512) {
        // ---- main path: logical (16 m, 8 n, 4 z), XCD-chunk swizzled ----
        const int l = (bid & 7) * 64 + (bid >> 3);
        const int m0 = (l & 15) * 128;
        const int n0 = ((l >> 4) & 7) * 64;
        const int z  = l >> 7;
        const int K = R_DIM, Kc = R_DIM / 4, k0 = z * Kc, NS = 512;
        unsigned short* part = mainp + (size_t)z * B_DIM * NS;
        f32x4 acc[4][2] = {};

        for (int kt = 0; kt < Kc; kt += 128) {
            const unsigned short* Ab = g_bf + (size_t)m0 * K + k0 + kt;
            const unsigned short* Bb = GAT  + (size_t)n0 * K + k0 + kt;
            #pragma unroll
            for (int q = 0; q < 8; q++) stage16(Alds, Ab, K, tid + q * 256);
            #pragma unroll
            for (int q = 0; q < 4; q++) stage16(Blds, Bb, K, tid + q * 256);
            __syncthreads();
            #pragma unroll
            for (int ks = 0; ks < 4; ks++) {
                const int k8 = ks * 4 + (lane >> 4);
                const int ra = wr * 64 + (lane & 15);
                const int rb = wc * 32 + (lane & 15);
                const int sa = (k8 ^ (ra & 15)) << 3;
                const int sb = (k8 ^ (rb & 15)) << 3;
                short8 a0 = *(const short8*)&Alds[(ra)      * 128 + sa];
                short8 a1 = *(const short8*)&Alds[(ra + 16) * 128 + sa];
                short8 a2 = *(const short8*)&Alds[(ra + 32) * 128 + sa];
                short8 a3 = *(const short8*)&Alds[(ra + 48) * 128 + sa];
                short8 b0 = *(const short8*)&Blds[(rb)      * 128 + sb];
                short8 b1 = *(const short8*)&Blds[(rb + 16) * 128 + sb];
                acc[0][0] = __builtin_amdgcn_mfma_f32_16x16x32_bf16(a0, b0, acc[0][0], 0, 0, 0);
                acc[0][1] = __builtin_amdgcn_mfma_f32_16x16x32_bf16(a0, b1, acc[0][1], 0, 0, 0);
                acc[1][0] = __builtin_amdgcn_mfma_f32_16x16x32_bf16(a1, b0, acc[1][0], 0, 0, 0);
                acc[1][1] = __builtin_amdgcn_mfma_f32_16x16x32_bf16(a1, b1, acc[1][1], 0, 0, 0);
                acc[2][0] = __builtin_amdgcn_mfma_f32_16x16x32_bf16(a2, b0, acc[2][0], 0, 0, 0);
                acc[2][1] = __builtin_amdgcn_mfma_f32_16x16x32_bf16(a2, b1, acc[2][1], 0, 0, 0);
                acc[3][0] = __builtin_amdgcn_mfma_f32_16x16x32_bf16(a3, b0, acc[3][0], 0, 0, 0);
                acc[3][1] = __builtin_amdgcn_mfma_f32_16x16x32_bf16(a3, b1, acc[3][1], 0, 0, 0);
            }
            __syncthreads();
        }
        const int rbase = (lane >> 4) * 4;
        const int cbase = lane & 15;
        #pragma unroll
        for (int i = 0; i < 4; i++) {
            #pragma unroll
            for (int j = 0; j < 2; j++) {
                const int gn = n0 + wc * 32 + j * 16 + cbase;
                #pragma unroll
                for (int q = 0; q < 4; q++) {
                    const int gm = m0 + wr * 64 + i * 16 + rbase + q;
                    part[(size_t)gm * NS + gn] = f2h(acc[i][j][q]);
                }
            }
        }
    } else {
        // ---- lam path: grid (32 m, 4 n, 2 z) ----
        const int l = bid - 512;
        const int m0 = (l & 31) * 64;
        const int n0 = ((l >> 5) & 3) * 64;
        const int z  = l >> 7;
        const int K = M_DIM, Kc = M_DIM / 2, k0 = z * Kc, NS = A_DIM;
        unsigned short* part = lamp + (size_t)z * B_DIM * NS;
        f32x4 acc[2][2] = {};

        // Kc = 128 -> single K-tile
        const unsigned short* Ab = mclip + (size_t)m0 * K + k0;
        const unsigned short* Bb = w_bf  + (size_t)n0 * K + k0;
        #pragma unroll
        for (int q = 0; q < 4; q++) {
            stage16(Alds, Ab, K, tid + q * 256);
            stage16(Blds, Bb, K, tid + q * 256);
        }
        __syncthreads();
        #pragma unroll
        for (int ks = 0; ks < 4; ks++) {
            const int k8 = ks * 4 + (lane >> 4);
            const int r0a = wr * 32 + (lane & 15);
            const int r0b = wc * 32 + (lane & 15);
            const int sa = (k8 ^ (r0a & 15)) << 3;
            const int sb = (k8 ^ (r0b & 15)) << 3;
            short8 a0 = *(const short8*)&Alds[(r0a)      * 128 + sa];
            short8 a1 = *(const short8*)&Alds[(r0a + 16) * 128 + sa];
            short8 b0 = *(const short8*)&Blds[(r0b)      * 128 + sb];
            short8 b1 = *(const short8*)&Blds[(r0b + 16) * 128 + sb];
            acc[0][0] = __builtin_amdgcn_mfma_f32_16x16x32_bf16(a0, b0, acc[0][0], 0, 0, 0);
            acc[0][1] = __builtin_amdgcn_mfma_f32_16x16x32_bf16(a0, b1, acc[0][1], 0, 0, 0);
            acc[1][0] = __builtin_amdgcn_mfma_f32_16x16x32_bf16(a1, b0, acc[1][0], 0, 0, 0);
            acc[1][1] = __builtin_amdgcn_mfma_f32_16x16x32_bf16(a1, b1, acc[1][1], 0, 0, 0);
        }
        const int rbase = (lane >> 4) * 4;
        const int cbase = lane & 15;
        #pragma unroll
        for (int i = 0; i < 2; i++) {
            #pragma unroll
            for (int j = 0; j < 2; j++) {
                const int gn = n0 + wc * 32 + j * 16 + cbase;
                #pragma unroll
                for (int q = 0; q < 4; q++) {
                    const int gm = m0 + wr * 32 + i * 16 + rbase + q;
                    part[(size_t)gm * NS + gn] = f2h(acc[i][j][q]);
                }
            }
        }
    }
}

// ---------------------------------------------------------------------------
// Epilogue: sum f16 split-K partials; relu(main); lam cols +=
// softplus(b + lam_ment). float4-out over 2048x512.
// ---------------------------------------------------------------------------
__global__ __launch_bounds__(256) void epilogue(
    const unsigned short* __restrict__ mainpart,
    const unsigned short* __restrict__ lampart,
    const float* __restrict__ bvec, float* __restrict__ outp)
{
    const int idx = blockIdx.x * 256 + threadIdx.x;   // over 2048*128
    const int m = idx >> 7, n4 = idx & 127;
    const size_t mb = (size_t)m * 128 + n4;           // ushort4 units (NS=512)
    const size_t zs = (size_t)B_DIM * 128;
    float sx = 0.0f, sy = 0.0f, sz = 0.0f, sw = 0.0f;
    #pragma unroll
    for (int z = 0; z < 4; z++) {
        ushort4 t = ((const ushort4*)mainpart)[mb + z * zs];
        sx += h2f(t.x); sy += h2f(t.y); sz += h2f(t.z); sw += h2f(t.w);
    }
    sx = fmaxf(sx, 0.0f); sy = fmaxf(sy, 0.0f);
    sz = fmaxf(sz, 0.0f); sw = fmaxf(sw, 0.0f);
    if (n4 >= 64) {
        const int na = n4 - 64;                       // ushort4 idx in 256-col lam
        const size_t lb = (size_t)m * 64 + na;
        const size_t ls = (size_t)B_DIM * 64;
        ushort4 u0 = ((const ushort4*)lampart)[lb];
        ushort4 u1 = ((const ushort4*)lampart)[lb + ls];
        float4 bb = ((const float4*)bvec)[na];
        float x0 = bb.x + h2f(u0.x) + h2f(u1.x);
        float x1 = bb.y + h2f(u0.y) + h2f(u1.y);
        float x2 = bb.z + h2f(u0.z) + h2f(u1.z);
        float x3 = bb.w + h2f(u0.w) + h2f(u1.w);
        sx += (x0 > 20.0f) ? x0 : log1pf(__expf(x0));
        sy += (x1 > 20.0f) ? x1 : log1pf(__expf(x1));
        sz += (x2 > 20.0f) ? x2 : log1pf(__expf(x2));
        sw += (x3 > 20.0f) ? x3 : log1pf(__expf(x3));
    }
    float4 s; s.x = sx; s.y = sy; s.z = sz; s.w = sw;
    ((float4*)(outp + (size_t)m * OUT_STRIDE + 2048))[n4] = s;
}

// ---------------------------------------------------------------------------
extern "C" void kernel_launch(void* const* d_in, const int* in_sizes, int n_in,
                              void* d_out, int out_size, void* d_ws, size_t ws_size,
                              hipStream_t stream)
{
    const float* M_minus = (const float*)d_in[0];
    const float* amask   = (const float*)d_in[1];
    const float* gate    = (const float*)d_in[2];
    const float* bmask   = (const float*)d_in[3];
    const float* isM     = (const float*)d_in[4];
    const float* isA     = (const float*)d_in[5];
    const float* GA      = (const float*)d_in[6];
    const float* GB      = (const float*)d_in[7];
    const float* bvec    = (const float*)d_in[8];
    const float* w       = (const float*)d_in[9];
    const int*   bidx    = (const int*)d_in[10];
    const int*   hidx    = (const int*)d_in[11];
    float* outp = (float*)d_out;

    char* ws = (char*)d_ws;
    unsigned short* g_bf   = (unsigned short*)(ws + 0);          // 16 MiB
    unsigned short* GAT    = (unsigned short*)(ws + (16u<<20));  // 2 MiB
    unsigned short* GBT    = (unsigned short*)(ws + (18u<<20));  // 2 MiB (contiguous after GAT)
    unsigned short* w_bf   = (unsigned short*)(ws + (20u<<20));  // 128 KiB
    uint4*          meta   = (uint4*)(ws + (20u<<20) + (256u<<10)); // 64 KiB
    unsigned short* mclip  = (unsigned short*)(ws + (21u<<20));  // 1 MiB
    unsigned short* mainp  = (unsigned short*)(ws + (22u<<20));  // 4 x 2 MiB (f16)
    unsigned short* lamp   = (unsigned short*)(ws + (38u<<20));  // 2 x 1 MiB (f16)

    prep_meta<<<dim3(R_DIM / 256), dim3(256), 0, stream>>>(bidx, bmask, hidx, meta);
    main_fused<<<dim3(B_DIM / NB), dim3(1024), 0, stream>>>(
        M_minus, amask, gate, meta, GA, GB, isM, isA, w,
        GAT, GBT, w_bf, g_bf, mclip, outp);
    gemm_all<<<dim3(768), dim3(256), 0, stream>>>(
        g_bf, GAT, mclip, w_bf, mainp, lamp);
    epilogue<<<dim3((B_DIM * 128) / 256), dim3(256), 0, stream>>>(
        mainp, lamp, bvec, outp);
}

// Round 17
// 44.046 us; speedup vs baseline: 3.6421x; 1.0885x over previous
//
#include <hip/hip_runtime.h>

typedef __attribute__((ext_vector_type(8))) short short8;
typedef __attribute__((ext_vector_type(4))) float f32x4;

#define B_DIM 2048
#define P_DIM 2048
#define R_DIM 4096
#define H_DIM 6
#define M_DIM 256
#define A_DIM 256
#define OUT_STRIDE 2560   // P + M + A
#define NB 4              // batch rows per main_fused block (packed 4xbf16)

// exp2-form constants: e = exp2(-C1*val);  g = -K2*log2(sum e)*gate
#define C1 14.426950408889634f   // 10/ln2 = 1/(tau*ln2)
#define K2 0.06931471805599453f  // ln2/10
#define C2 7.213475204444817f    // 5/ln2
#define K3 0.13862943611198906f  // ln2/5

static __device__ __forceinline__ float fexp2(float x) { return __builtin_amdgcn_exp2f(x); }
static __device__ __forceinline__ float flog2(float x) { return __builtin_amdgcn_logf(x); }

static __device__ __forceinline__ unsigned short f2bf(float f) {
    unsigned u = __builtin_bit_cast(unsigned, f);
    u += 0x7fffu + ((u >> 16) & 1u);          // round-to-nearest-even
    return (unsigned short)(u >> 16);
}
static __device__ __forceinline__ float bf2f_lo(unsigned u) {   // low bf16 -> f32
    return __builtin_bit_cast(float, u << 16);
}
static __device__ __forceinline__ float bf2f_hi(unsigned u) {   // high bf16 -> f32
    return __builtin_bit_cast(float, u & 0xFFFF0000u);
}
static __device__ __forceinline__ unsigned short f2h(float f) {
    return __builtin_bit_cast(unsigned short, (_Float16)f);
}
static __device__ __forceinline__ float h2f(unsigned short u) {
    return (float)__builtin_bit_cast(_Float16, u);
}

// ---------------------------------------------------------------------------
// Main fused kernel: NB=4 rows/block, 1024 threads, grid 512 = exactly
// 2 blocks/CU resident (32 waves/CU).
// vrowu4[p] = uint2 of 4x bf16 e-values, e = exp2(-C1*val): per-instance
// softmin needs only SUM of gathered e. Masked sentinel index -> 2048 where
// e=0. s>0 guaranteed (body_mask[:,0]==1).
// Rule metadata (bidx/bmask/hidx) is consumed DIRECTLY from the (L2-resident,
// 208 KB total) inputs in phase 2 — no separate prep_meta kernel.
// ---------------------------------------------------------------------------
__global__ __launch_bounds__(1024, 8) void main_fused(
    const float* __restrict__ M_minus, const float* __restrict__ amask,
    const float* __restrict__ gate,
    const int* __restrict__ bidx, const float* __restrict__ bmask,
    const int* __restrict__ hidx,
    const float* __restrict__ GA, const float* __restrict__ GB,
    const float* __restrict__ isM, const float* __restrict__ isA,
    const float* __restrict__ w,
    unsigned short* __restrict__ GAT, unsigned short* __restrict__ GBT,
    unsigned short* __restrict__ wb,
    unsigned short* __restrict__ g_bf, unsigned short* __restrict__ mclip_bf,
    float* __restrict__ outp)
{
    __shared__ __align__(16) union SM {
        struct {
            uint2 vrowu4[2052];          // [p] = 4x bf16 e-values
            float shead[NB][M_DIM];
        } mf;
        float prep[4][32][33];
    } sm;
    const int bid = blockIdx.x;
    const int tid = threadIdx.x;
    const int b0 = bid * NB;

    // ---- fused prep: 512 blocks x 4 transpose units (=2048); w on 0..63 ----
    {
        const int s = tid >> 8, lt = tid & 255;
        const int u = bid * 4 + s;                 // 0..2047
        const int tx = lt & 31, ty = lt >> 5;
        const int which = u >> 10;
        const int rem = u & 1023;
        const float* src = which ? GB : GA;
        const float* scv = which ? isA : isM;
        const int r0 = (rem >> 3) * 32;            // K (=R) dim
        const int n0 = (rem & 7) * 32;             // N (=256) dim
        #pragma unroll
        for (int q = 0; q < 4; q++) {
            int rr = ty + q * 8;
            sm.prep[s][rr][tx] = scv[r0 + rr] * src[(size_t)(r0 + rr) * 256 + n0 + tx];
        }
        __syncthreads();
        unsigned short* dst = which ? GBT : GAT;
        #pragma unroll
        for (int q = 0; q < 4; q++) {
            int nn = ty + q * 8;
            dst[(size_t)(n0 + nn) * R_DIM + r0 + tx] = f2bf(sm.prep[s][tx][nn]);
        }
        if (bid < 64) {
            const int i = bid * 1024 + tid;        // 65536 total
            wb[i] = f2bf(w[i]);
        }
        __syncthreads();   // protect LDS reuse by mf phases
    }

    // ---- mf init ----
    if (tid < NB * M_DIM) sm.mf.shead[tid >> 8][tid & 255] = 0.0f;
    if (tid == 0) sm.mf.vrowu4[2048] = make_uint2(0u, 0u);   // sentinel e=0

    // phase 1: each thread builds p0=2t, p0+1 for all 4 rows (e packed bf16)
    {
        const int p0 = tid * 2;
        float2 a[NB];
        #pragma unroll
        for (int r = 0; r < NB; r++)
            a[r] = *(const float2*)(amask + (size_t)(b0 + r) * P_DIM + p0);
        if (tid < M_DIM / 2) {
            #pragma unroll
            for (int r = 0; r < NB; r++) {
                float2 m = *(const float2*)(M_minus + (size_t)(b0 + r) * M_DIM + p0);
                float mc0 = fminf(fmaxf(m.x, 0.0f), 1.0f);
                float mc1 = fminf(fmaxf(m.y, 0.0f), 1.0f);
                ushort2 wv; wv.x = f2bf(mc0); wv.y = f2bf(mc1);
                *(ushort2*)(mclip_bf + (size_t)(b0 + r) * M_DIM + p0) = wv;
                a[r].x = fmaxf(mc0, a[r].x);
                a[r].y = fmaxf(mc1, a[r].y);
            }
        }
        float e0[NB], e1[NB];
        #pragma unroll
        for (int r = 0; r < NB; r++) {
            e0[r] = fexp2(-C1 * a[r].x);
            e1[r] = fexp2(-C1 * a[r].y);
        }
        uint4 pk;
        pk.x = (unsigned)f2bf(e0[0]) | ((unsigned)f2bf(e0[1]) << 16);
        pk.y = (unsigned)f2bf(e0[2]) | ((unsigned)f2bf(e0[3]) << 16);
        pk.z = (unsigned)f2bf(e1[0]) | ((unsigned)f2bf(e1[1]) << 16);
        pk.w = (unsigned)f2bf(e1[2]) | ((unsigned)f2bf(e1[3]) << 16);
        *(uint4*)&sm.mf.vrowu4[p0] = pk;
    }
    __syncthreads();

    // phase 2: rules, 4 iterations. Rule metadata loaded inline (L2-resident):
    // bidx int2 x3 + bmask float2 x3 + hidx; masked -> sentinel 2048.
    // 6 x ds_read_b64 gathers each serving 4 rows; s = sum of gathered e.
    #pragma unroll
    for (int it = 0; it < R_DIM / 1024; it++) {
        const int rr = tid + it * 1024;
        const int2*   bi2 = (const int2*)bidx + rr * 3;
        const float2* bm2 = (const float2*)bmask + rr * 3;
        int2 i01 = bi2[0], i23 = bi2[1], i45 = bi2[2];
        float2 m01 = bm2[0], m23 = bm2[1], m45 = bm2[2];
        const int hh = hidx[rr];
        float gv[NB];
        #pragma unroll
        for (int r = 0; r < NB; r++)
            gv[r] = gate[(size_t)(b0 + r) * R_DIM + rr];
        const int i0 = (m01.x > 0.0f) ? i01.x : 2048;
        const int i1 = (m01.y > 0.0f) ? i01.y : 2048;
        const int i2 = (m23.x > 0.0f) ? i23.x : 2048;
        const int i3 = (m23.y > 0.0f) ? i23.y : 2048;
        const int i4 = (m45.x > 0.0f) ? i45.x : 2048;
        const int i5 = (m45.y > 0.0f) ? i45.y : 2048;
        uint2 u0 = sm.mf.vrowu4[i0], u1 = sm.mf.vrowu4[i1], u2 = sm.mf.vrowu4[i2];
        uint2 u3 = sm.mf.vrowu4[i3], u4 = sm.mf.vrowu4[i4], u5 = sm.mf.vrowu4[i5];

        float s0 = bf2f_lo(u0.x) + bf2f_lo(u1.x) + bf2f_lo(u2.x)
                 + bf2f_lo(u3.x) + bf2f_lo(u4.x) + bf2f_lo(u5.x);
        float s1 = bf2f_hi(u0.x) + bf2f_hi(u1.x) + bf2f_hi(u2.x)
                 + bf2f_hi(u3.x) + bf2f_hi(u4.x) + bf2f_hi(u5.x);
        float s2 = bf2f_lo(u0.y) + bf2f_lo(u1.y) + bf2f_lo(u2.y)
                 + bf2f_lo(u3.y) + bf2f_lo(u4.y) + bf2f_lo(u5.y);
        float s3 = bf2f_hi(u0.y) + bf2f_hi(u1.y) + bf2f_hi(u2.y)
                 + bf2f_hi(u3.y) + bf2f_hi(u4.y) + bf2f_hi(u5.y);
        float gg0 = flog2(s0) * (-K2 * gv[0]);
        float gg1 = flog2(s1) * (-K2 * gv[1]);
        float gg2 = flog2(s2) * (-K2 * gv[2]);
        float gg3 = flog2(s3) * (-K2 * gv[3]);
        g_bf[(size_t)b0 * R_DIM + rr]       = f2bf(gg0);
        g_bf[(size_t)(b0 + 1) * R_DIM + rr] = f2bf(gg1);
        g_bf[(size_t)(b0 + 2) * R_DIM + rr] = f2bf(gg2);
        g_bf[(size_t)(b0 + 3) * R_DIM + rr] = f2bf(gg3);
        if (hh < M_DIM) {
            atomicAdd(&sm.mf.shead[0][hh], fexp2(gg0 * C2));
            atomicAdd(&sm.mf.shead[1][hh], fexp2(gg1 * C2));
            atomicAdd(&sm.mf.shead[2][hh], fexp2(gg2 * C2));
            atomicAdd(&sm.mf.shead[3][hh], fexp2(gg3 * C2));
        }
    }
    __syncthreads();

    // phase 3: val_new columns of out (val = -K2*log2(e))
    {
        const int p0 = tid * 2;
        uint4 uu = *(const uint4*)&sm.mf.vrowu4[p0];
        float v[NB][2];
        v[0][0] = -K2 * flog2(bf2f_lo(uu.x)); v[1][0] = -K2 * flog2(bf2f_hi(uu.x));
        v[2][0] = -K2 * flog2(bf2f_lo(uu.y)); v[3][0] = -K2 * flog2(bf2f_hi(uu.y));
        v[0][1] = -K2 * flog2(bf2f_lo(uu.z)); v[1][1] = -K2 * flog2(bf2f_hi(uu.z));
        v[2][1] = -K2 * flog2(bf2f_lo(uu.w)); v[3][1] = -K2 * flog2(bf2f_hi(uu.w));
        if (tid < M_DIM / 2) {
            #pragma unroll
            for (int r = 0; r < NB; r++) {
                float sa = sm.mf.shead[r][p0], sb = sm.mf.shead[r][p0 + 1];
                if (sa > 0.0f) v[r][0] = fmaxf(v[r][0], K3 * flog2(sa));
                if (sb > 0.0f) v[r][1] = fmaxf(v[r][1], K3 * flog2(sb));
            }
        }
        #pragma unroll
        for (int r = 0; r < NB; r++)
            *(float2*)(outp + (size_t)(b0 + r) * OUT_STRIDE + p0) =
                make_float2(v[r][0], v[r][1]);
    }
}

// ---------------------------------------------------------------------------
// global_load_lds 16B staging, XOR-swizzled source, linear LDS dest. BK=128.
// ---------------------------------------------------------------------------
__device__ __forceinline__ void stage16(unsigned short* lds,
                                        const unsigned short* gsrc,
                                        int K, int c)
{
    const int row = c >> 4, slot = c & 15;
    const int k8 = slot ^ (row & 15);      // logical 16B chunk at this slot
    __builtin_amdgcn_global_load_lds(
        (const __attribute__((address_space(1))) void*)(gsrc + (size_t)row * K + k8 * 8),
        (__attribute__((address_space(3))) void*)(lds + c * 8), 16, 0, 0);
}

// ---------------------------------------------------------------------------
// Merged GEMM kernel, 768 blocks x 256 threads, f16 partials (r9 shape):
//   bid < 512 : main [S|lam_logic]: BM=128,BN=64,BK=128, K=4096, z=4,
//               logical (16 m, 8 n, 4 z), XCD-chunk swizzled.
//   bid >= 512: lam_ment: BM=64,BN=64,BK=128, K=256, z=2.
// ---------------------------------------------------------------------------
__global__ __launch_bounds__(256) void gemm_all(
    const unsigned short* __restrict__ g_bf,
    const unsigned short* __restrict__ GAT,
    const unsigned short* __restrict__ mclip,
    const unsigned short* __restrict__ w_bf,
    unsigned short* __restrict__ mainp, unsigned short* __restrict__ lamp)
{
    __shared__ __align__(16) unsigned short Alds[128 * 128];
    __shared__ __align__(16) unsigned short Blds[64 * 128];
    const int bid = blockIdx.x;
    const int tid = threadIdx.x;
    const int lane = tid & 63, wid = tid >> 6;
    const int wr = wid >> 1, wc = wid & 1;

    if (bid < 512) {
        // ---- main path: logical (16 m, 8 n, 4 z), XCD-chunk swizzled ----
        const int l = (bid & 7) * 64 + (bid >> 3);
        const int m0 = (l & 15) * 128;
        const int n0 = ((l >> 4) & 7) * 64;
        const int z  = l >> 7;
        const int K = R_DIM, Kc = R_DIM / 4, k0 = z * Kc, NS = 512;
        unsigned short* part = mainp + (size_t)z * B_DIM * NS;
        f32x4 acc[4][2] = {};

        for (int kt = 0; kt < Kc; kt += 128) {
            const unsigned short* Ab = g_bf + (size_t)m0 * K + k0 + kt;
            const unsigned short* Bb = GAT  + (size_t)n0 * K + k0 + kt;
            #pragma unroll
            for (int q = 0; q < 8; q++) stage16(Alds, Ab, K, tid + q * 256);
            #pragma unroll
            for (int q = 0; q < 4; q++) stage16(Blds, Bb, K, tid + q * 256);
            __syncthreads();
            #pragma unroll
            for (int ks = 0; ks < 4; ks++) {
                const int k8 = ks * 4 + (lane >> 4);
                const int ra = wr * 64 + (lane & 15);
                const int rb = wc * 32 + (lane & 15);
                const int sa = (k8 ^ (ra & 15)) << 3;
                const int sb = (k8 ^ (rb & 15)) << 3;
                short8 a0 = *(const short8*)&Alds[(ra)      * 128 + sa];
                short8 a1 = *(const short8*)&Alds[(ra + 16) * 128 + sa];
                short8 a2 = *(const short8*)&Alds[(ra + 32) * 128 + sa];
                short8 a3 = *(const short8*)&Alds[(ra + 48) * 128 + sa];
                short8 b0 = *(const short8*)&Blds[(rb)      * 128 + sb];
                short8 b1 = *(const short8*)&Blds[(rb + 16) * 128 + sb];
                acc[0][0] = __builtin_amdgcn_mfma_f32_16x16x32_bf16(a0, b0, acc[0][0], 0, 0, 0);
                acc[0][1] = __builtin_amdgcn_mfma_f32_16x16x32_bf16(a0, b1, acc[0][1], 0, 0, 0);
                acc[1][0] = __builtin_amdgcn_mfma_f32_16x16x32_bf16(a1, b0, acc[1][0], 0, 0, 0);
                acc[1][1] = __builtin_amdgcn_mfma_f32_16x16x32_bf16(a1, b1, acc[1][1], 0, 0, 0);
                acc[2][0] = __builtin_amdgcn_mfma_f32_16x16x32_bf16(a2, b0, acc[2][0], 0, 0, 0);
                acc[2][1] = __builtin_amdgcn_mfma_f32_16x16x32_bf16(a2, b1, acc[2][1], 0, 0, 0);
                acc[3][0] = __builtin_amdgcn_mfma_f32_16x16x32_bf16(a3, b0, acc[3][0], 0, 0, 0);
                acc[3][1] = __builtin_amdgcn_mfma_f32_16x16x32_bf16(a3, b1, acc[3][1], 0, 0, 0);
            }
            __syncthreads();
        }
        const int rbase = (lane >> 4) * 4;
        const int cbase = lane & 15;
        #pragma unroll
        for (int i = 0; i < 4; i++) {
            #pragma unroll
            for (int j = 0; j < 2; j++) {
                const int gn = n0 + wc * 32 + j * 16 + cbase;
                #pragma unroll
                for (int q = 0; q < 4; q++) {
                    const int gm = m0 + wr * 64 + i * 16 + rbase + q;
                    part[(size_t)gm * NS + gn] = f2h(acc[i][j][q]);
                }
            }
        }
    } else {
        // ---- lam path: grid (32 m, 4 n, 2 z) ----
        const int l = bid - 512;
        const int m0 = (l & 31) * 64;
        const int n0 = ((l >> 5) & 3) * 64;
        const int z  = l >> 7;
        const int K = M_DIM, Kc = M_DIM / 2, k0 = z * Kc, NS = A_DIM;
        unsigned short* part = lamp + (size_t)z * B_DIM * NS;
        f32x4 acc[2][2] = {};

        // Kc = 128 -> single K-tile
        const unsigned short* Ab = mclip + (size_t)m0 * K + k0;
        const unsigned short* Bb = w_bf  + (size_t)n0 * K + k0;
        #pragma unroll
        for (int q = 0; q < 4; q++) {
            stage16(Alds, Ab, K, tid + q * 256);
            stage16(Blds, Bb, K, tid + q * 256);
        }
        __syncthreads();
        #pragma unroll
        for (int ks = 0; ks < 4; ks++) {
            const int k8 = ks * 4 + (lane >> 4);
            const int r0a = wr * 32 + (lane & 15);
            const int r0b = wc * 32 + (lane & 15);
            const int sa = (k8 ^ (r0a & 15)) << 3;
            const int sb = (k8 ^ (r0b & 15)) << 3;
            short8 a0 = *(const short8*)&Alds[(r0a)      * 128 + sa];
            short8 a1 = *(const short8*)&Alds[(r0a + 16) * 128 + sa];
            short8 b0 = *(const short8*)&Blds[(r0b)      * 128 + sb];
            short8 b1 = *(const short8*)&Blds[(r0b + 16) * 128 + sb];
            acc[0][0] = __builtin_amdgcn_mfma_f32_16x16x32_bf16(a0, b0, acc[0][0], 0, 0, 0);
            acc[0][1] = __builtin_amdgcn_mfma_f32_16x16x32_bf16(a0, b1, acc[0][1], 0, 0, 0);
            acc[1][0] = __builtin_amdgcn_mfma_f32_16x16x32_bf16(a1, b0, acc[1][0], 0, 0, 0);
            acc[1][1] = __builtin_amdgcn_mfma_f32_16x16x32_bf16(a1, b1, acc[1][1], 0, 0, 0);
        }
        const int rbase = (lane >> 4) * 4;
        const int cbase = lane & 15;
        #pragma unroll
        for (int i = 0; i < 2; i++) {
            #pragma unroll
            for (int j = 0; j < 2; j++) {
                const int gn = n0 + wc * 32 + j * 16 + cbase;
                #pragma unroll
                for (int q = 0; q < 4; q++) {
                    const int gm = m0 + wr * 32 + i * 16 + rbase + q;
                    part[(size_t)gm * NS + gn] = f2h(acc[i][j][q]);
                }
            }
        }
    }
}

// ---------------------------------------------------------------------------
// Epilogue: sum f16 split-K partials; relu(main); lam cols +=
// softplus(b + lam_ment). float4-out over 2048x512.
// ---------------------------------------------------------------------------
__global__ __launch_bounds__(256) void epilogue(
    const unsigned short* __restrict__ mainpart,
    const unsigned short* __restrict__ lampart,
    const float* __restrict__ bvec, float* __restrict__ outp)
{
    const int idx = blockIdx.x * 256 + threadIdx.x;   // over 2048*128
    const int m = idx >> 7, n4 = idx & 127;
    const size_t mb = (size_t)m * 128 + n4;           // ushort4 units (NS=512)
    const size_t zs = (size_t)B_DIM * 128;
    float sx = 0.0f, sy = 0.0f, sz = 0.0f, sw = 0.0f;
    #pragma unroll
    for (int z = 0; z < 4; z++) {
        ushort4 t = ((const ushort4*)mainpart)[mb + z * zs];
        sx += h2f(t.x); sy += h2f(t.y); sz += h2f(t.z); sw += h2f(t.w);
    }
    sx = fmaxf(sx, 0.0f); sy = fmaxf(sy, 0.0f);
    sz = fmaxf(sz, 0.0f); sw = fmaxf(sw, 0.0f);
    if (n4 >= 64) {
        const int na = n4 - 64;                       // ushort4 idx in 256-col lam
        const size_t lb = (size_t)m * 64 + na;
        const size_t ls = (size_t)B_DIM * 64;
        ushort4 u0 = ((const ushort4*)lampart)[lb];
        ushort4 u1 = ((const ushort4*)lampart)[lb + ls];
        float4 bb = ((const float4*)bvec)[na];
        float x0 = bb.x + h2f(u0.x) + h2f(u1.x);
        float x1 = bb.y + h2f(u0.y) + h2f(u1.y);
        float x2 = bb.z + h2f(u0.z) + h2f(u1.z);
        float x3 = bb.w + h2f(u0.w) + h2f(u1.w);
        sx += (x0 > 20.0f) ? x0 : log1pf(__expf(x0));
        sy += (x1 > 20.0f) ? x1 : log1pf(__expf(x1));
        sz += (x2 > 20.0f) ? x2 : log1pf(__expf(x2));
        sw += (x3 > 20.0f) ? x3 : log1pf(__expf(x3));
    }
    float4 s; s.x = sx; s.y = sy; s.z = sz; s.w = sw;
    ((float4*)(outp + (size_t)m * OUT_STRIDE + 2048))[n4] = s;
}

// ---------------------------------------------------------------------------
extern "C" void kernel_launch(void* const* d_in, const int* in_sizes, int n_in,
                              void* d_out, int out_size, void* d_ws, size_t ws_size,
                              hipStream_t stream)
{
    const float* M_minus = (const float*)d_in[0];
    const float* amask   = (const float*)d_in[1];
    const float* gate    = (const float*)d_in[2];
    const float* bmask   = (const float*)d_in[3];
    const float* isM     = (const float*)d_in[4];
    const float* isA     = (const float*)d_in[5];
    const float* GA      = (const float*)d_in[6];
    const float* GB      = (const float*)d_in[7];
    const float* bvec    = (const float*)d_in[8];
    const float* w       = (const float*)d_in[9];
    const int*   bidx    = (const int*)d_in[10];
    const int*   hidx    = (const int*)d_in[11];
    float* outp = (float*)d_out;

    char* ws = (char*)d_ws;
    unsigned short* g_bf   = (unsigned short*)(ws + 0);          // 16 MiB
    unsigned short* GAT    = (unsigned short*)(ws + (16u<<20));  // 2 MiB
    unsigned short* GBT    = (unsigned short*)(ws + (18u<<20));  // 2 MiB (contiguous after GAT)
    unsigned short* w_bf   = (unsigned short*)(ws + (20u<<20));  // 128 KiB
    unsigned short* mclip  = (unsigned short*)(ws + (21u<<20));  // 1 MiB
    unsigned short* mainp  = (unsigned short*)(ws + (22u<<20));  // 4 x 2 MiB (f16)
    unsigned short* lamp   = (unsigned short*)(ws + (38u<<20));  // 2 x 1 MiB (f16)

    main_fused<<<dim3(B_DIM / NB), dim3(1024), 0, stream>>>(
        M_minus, amask, gate, bidx, bmask, hidx, GA, GB, isM, isA, w,
        GAT, GBT, w_bf, g_bf, mclip, outp);
    gemm_all<<<dim3(768), dim3(256), 0, stream>>>(
        g_bf, GAT, mclip, w_bf, mainp, lamp);
    epilogue<<<dim3((B_DIM * 128) / 256), dim3(256), 0, stream>>>(
        mainp, lamp, bvec, outp);
}

// Round 18
// 43.759 us; speedup vs baseline: 3.6660x; 1.0066x over previous
//
#include <hip/hip_runtime.h>

typedef __attribute__((ext_vector_type(8))) short short8;
typedef __attribute__((ext_vector_type(4))) float f32x4;

#define B_DIM 2048
#define P_DIM 2048
#define R_DIM 4096
#define H_DIM 6
#define M_DIM 256
#define A_DIM 256
#define OUT_STRIDE 2560   // P + M + A
#define NB 4              // batch rows per main_fused block (packed 4xbf16)

// exp2-form constants: e = exp2(-C1*val);  g = -K2*log2(sum e)*gate
#define C1 14.426950408889634f   // 10/ln2 = 1/(tau*ln2)
#define K2 0.06931471805599453f  // ln2/10
#define C2 7.213475204444817f    // 5/ln2
#define K3 0.13862943611198906f  // ln2/5

static __device__ __forceinline__ float fexp2(float x) { return __builtin_amdgcn_exp2f(x); }
static __device__ __forceinline__ float flog2(float x) { return __builtin_amdgcn_logf(x); }

static __device__ __forceinline__ unsigned short f2bf(float f) {
    unsigned u = __builtin_bit_cast(unsigned, f);
    u += 0x7fffu + ((u >> 16) & 1u);          // round-to-nearest-even
    return (unsigned short)(u >> 16);
}
static __device__ __forceinline__ float bf2f_lo(unsigned u) {   // low bf16 -> f32
    return __builtin_bit_cast(float, u << 16);
}
static __device__ __forceinline__ float bf2f_hi(unsigned u) {   // high bf16 -> f32
    return __builtin_bit_cast(float, u & 0xFFFF0000u);
}
static __device__ __forceinline__ unsigned short f2h(float f) {
    return __builtin_bit_cast(unsigned short, (_Float16)f);
}
static __device__ __forceinline__ float h2f(unsigned short u) {
    return (float)__builtin_bit_cast(_Float16, u);
}

// ---------------------------------------------------------------------------
// Main fused kernel: NB=4 rows/block, 1024 threads, grid 512 = exactly
// 2 blocks/CU resident (32 waves/CU).
// vrowu4[p] = uint2 of 4x bf16 e-values, e = exp2(-C1*val): per-instance
// softmin needs only SUM of gathered e. Masked sentinel index -> 2048 where
// e=0. s>0 guaranteed (body_mask[:,0]==1).
// Rule metadata (bidx/bmask/hidx) consumed DIRECTLY from L2-resident inputs.
// ---------------------------------------------------------------------------
__global__ __launch_bounds__(1024, 8) void main_fused(
    const float* __restrict__ M_minus, const float* __restrict__ amask,
    const float* __restrict__ gate,
    const int* __restrict__ bidx, const float* __restrict__ bmask,
    const int* __restrict__ hidx,
    const float* __restrict__ GA, const float* __restrict__ GB,
    const float* __restrict__ isM, const float* __restrict__ isA,
    const float* __restrict__ w,
    unsigned short* __restrict__ GAT, unsigned short* __restrict__ GBT,
    unsigned short* __restrict__ wb,
    unsigned short* __restrict__ g_bf, unsigned short* __restrict__ mclip_bf,
    float* __restrict__ outp)
{
    __shared__ __align__(16) union SM {
        struct {
            uint2 vrowu4[2052];          // [p] = 4x bf16 e-values
            float shead[NB][M_DIM];
        } mf;
        float prep[4][32][33];
    } sm;
    const int bid = blockIdx.x;
    const int tid = threadIdx.x;
    const int b0 = bid * NB;

    // ---- fused prep: 512 blocks x 4 transpose units (=2048); w on 0..63 ----
    {
        const int s = tid >> 8, lt = tid & 255;
        const int u = bid * 4 + s;                 // 0..2047
        const int tx = lt & 31, ty = lt >> 5;
        const int which = u >> 10;
        const int rem = u & 1023;
        const float* src = which ? GB : GA;
        const float* scv = which ? isA : isM;
        const int r0 = (rem >> 3) * 32;            // K (=R) dim
        const int n0 = (rem & 7) * 32;             // N (=256) dim
        #pragma unroll
        for (int q = 0; q < 4; q++) {
            int rr = ty + q * 8;
            sm.prep[s][rr][tx] = scv[r0 + rr] * src[(size_t)(r0 + rr) * 256 + n0 + tx];
        }
        __syncthreads();
        unsigned short* dst = which ? GBT : GAT;
        #pragma unroll
        for (int q = 0; q < 4; q++) {
            int nn = ty + q * 8;
            dst[(size_t)(n0 + nn) * R_DIM + r0 + tx] = f2bf(sm.prep[s][tx][nn]);
        }
        if (bid < 64) {
            const int i = bid * 1024 + tid;        // 65536 total
            wb[i] = f2bf(w[i]);
        }
        __syncthreads();   // protect LDS reuse by mf phases
    }

    // ---- mf init ----
    if (tid < NB * M_DIM) sm.mf.shead[tid >> 8][tid & 255] = 0.0f;
    if (tid == 0) sm.mf.vrowu4[2048] = make_uint2(0u, 0u);   // sentinel e=0

    // phase 1: each thread builds p0=2t, p0+1 for all 4 rows (e packed bf16)
    {
        const int p0 = tid * 2;
        float2 a[NB];
        #pragma unroll
        for (int r = 0; r < NB; r++)
            a[r] = *(const float2*)(amask + (size_t)(b0 + r) * P_DIM + p0);
        if (tid < M_DIM / 2) {
            #pragma unroll
            for (int r = 0; r < NB; r++) {
                float2 m = *(const float2*)(M_minus + (size_t)(b0 + r) * M_DIM + p0);
                float mc0 = fminf(fmaxf(m.x, 0.0f), 1.0f);
                float mc1 = fminf(fmaxf(m.y, 0.0f), 1.0f);
                ushort2 wv; wv.x = f2bf(mc0); wv.y = f2bf(mc1);
                *(ushort2*)(mclip_bf + (size_t)(b0 + r) * M_DIM + p0) = wv;
                a[r].x = fmaxf(mc0, a[r].x);
                a[r].y = fmaxf(mc1, a[r].y);
            }
        }
        float e0[NB], e1[NB];
        #pragma unroll
        for (int r = 0; r < NB; r++) {
            e0[r] = fexp2(-C1 * a[r].x);
            e1[r] = fexp2(-C1 * a[r].y);
        }
        uint4 pk;
        pk.x = (unsigned)f2bf(e0[0]) | ((unsigned)f2bf(e0[1]) << 16);
        pk.y = (unsigned)f2bf(e0[2]) | ((unsigned)f2bf(e0[3]) << 16);
        pk.z = (unsigned)f2bf(e1[0]) | ((unsigned)f2bf(e1[1]) << 16);
        pk.w = (unsigned)f2bf(e1[2]) | ((unsigned)f2bf(e1[3]) << 16);
        *(uint4*)&sm.mf.vrowu4[p0] = pk;
    }
    __syncthreads();

    // phase 2: rules, 4 iterations. Rule metadata loaded inline (L2-resident).
    #pragma unroll
    for (int it = 0; it < R_DIM / 1024; it++) {
        const int rr = tid + it * 1024;
        const int2*   bi2 = (const int2*)bidx + rr * 3;
        const float2* bm2 = (const float2*)bmask + rr * 3;
        int2 i01 = bi2[0], i23 = bi2[1], i45 = bi2[2];
        float2 m01 = bm2[0], m23 = bm2[1], m45 = bm2[2];
        const int hh = hidx[rr];
        float gv[NB];
        #pragma unroll
        for (int r = 0; r < NB; r++)
            gv[r] = gate[(size_t)(b0 + r) * R_DIM + rr];
        const int i0 = (m01.x > 0.0f) ? i01.x : 2048;
        const int i1 = (m01.y > 0.0f) ? i01.y : 2048;
        const int i2 = (m23.x > 0.0f) ? i23.x : 2048;
        const int i3 = (m23.y > 0.0f) ? i23.y : 2048;
        const int i4 = (m45.x > 0.0f) ? i45.x : 2048;
        const int i5 = (m45.y > 0.0f) ? i45.y : 2048;
        uint2 u0 = sm.mf.vrowu4[i0], u1 = sm.mf.vrowu4[i1], u2 = sm.mf.vrowu4[i2];
        uint2 u3 = sm.mf.vrowu4[i3], u4 = sm.mf.vrowu4[i4], u5 = sm.mf.vrowu4[i5];

        float s0 = bf2f_lo(u0.x) + bf2f_lo(u1.x) + bf2f_lo(u2.x)
                 + bf2f_lo(u3.x) + bf2f_lo(u4.x) + bf2f_lo(u5.x);
        float s1 = bf2f_hi(u0.x) + bf2f_hi(u1.x) + bf2f_hi(u2.x)
                 + bf2f_hi(u3.x) + bf2f_hi(u4.x) + bf2f_hi(u5.x);
        float s2 = bf2f_lo(u0.y) + bf2f_lo(u1.y) + bf2f_lo(u2.y)
                 + bf2f_lo(u3.y) + bf2f_lo(u4.y) + bf2f_lo(u5.y);
        float s3 = bf2f_hi(u0.y) + bf2f_hi(u1.y) + bf2f_hi(u2.y)
                 + bf2f_hi(u3.y) + bf2f_hi(u4.y) + bf2f_hi(u5.y);
        float gg0 = flog2(s0) * (-K2 * gv[0]);
        float gg1 = flog2(s1) * (-K2 * gv[1]);
        float gg2 = flog2(s2) * (-K2 * gv[2]);
        float gg3 = flog2(s3) * (-K2 * gv[3]);
        g_bf[(size_t)b0 * R_DIM + rr]       = f2bf(gg0);
        g_bf[(size_t)(b0 + 1) * R_DIM + rr] = f2bf(gg1);
        g_bf[(size_t)(b0 + 2) * R_DIM + rr] = f2bf(gg2);
        g_bf[(size_t)(b0 + 3) * R_DIM + rr] = f2bf(gg3);
        if (hh < M_DIM) {
            atomicAdd(&sm.mf.shead[0][hh], fexp2(gg0 * C2));
            atomicAdd(&sm.mf.shead[1][hh], fexp2(gg1 * C2));
            atomicAdd(&sm.mf.shead[2][hh], fexp2(gg2 * C2));
            atomicAdd(&sm.mf.shead[3][hh], fexp2(gg3 * C2));
        }
    }
    __syncthreads();

    // phase 3: val_new columns of out (val = -K2*log2(e))
    {
        const int p0 = tid * 2;
        uint4 uu = *(const uint4*)&sm.mf.vrowu4[p0];
        float v[NB][2];
        v[0][0] = -K2 * flog2(bf2f_lo(uu.x)); v[1][0] = -K2 * flog2(bf2f_hi(uu.x));
        v[2][0] = -K2 * flog2(bf2f_lo(uu.y)); v[3][0] = -K2 * flog2(bf2f_hi(uu.y));
        v[0][1] = -K2 * flog2(bf2f_lo(uu.z)); v[1][1] = -K2 * flog2(bf2f_hi(uu.z));
        v[2][1] = -K2 * flog2(bf2f_lo(uu.w)); v[3][1] = -K2 * flog2(bf2f_hi(uu.w));
        if (tid < M_DIM / 2) {
            #pragma unroll
            for (int r = 0; r < NB; r++) {
                float sa = sm.mf.shead[r][p0], sb = sm.mf.shead[r][p0 + 1];
                if (sa > 0.0f) v[r][0] = fmaxf(v[r][0], K3 * flog2(sa));
                if (sb > 0.0f) v[r][1] = fmaxf(v[r][1], K3 * flog2(sb));
            }
        }
        #pragma unroll
        for (int r = 0; r < NB; r++)
            *(float2*)(outp + (size_t)(b0 + r) * OUT_STRIDE + p0) =
                make_float2(v[r][0], v[r][1]);
    }
}

// ---------------------------------------------------------------------------
// global_load_lds 16B staging, XOR-swizzled source, linear LDS dest. BK=128.
// ---------------------------------------------------------------------------
__device__ __forceinline__ void stage16(unsigned short* lds,
                                        const unsigned short* gsrc,
                                        int K, int c)
{
    const int row = c >> 4, slot = c & 15;
    const int k8 = slot ^ (row & 15);      // logical 16B chunk at this slot
    __builtin_amdgcn_global_load_lds(
        (const __attribute__((address_space(1))) void*)(gsrc + (size_t)row * K + k8 * 8),
        (__attribute__((address_space(3))) void*)(lds + c * 8), 16, 0, 0);
}

// ---------------------------------------------------------------------------
// Merged GEMM kernel, 640 blocks x 256 threads, f16 partials:
//   bid < 512 : main [S|lam_logic]: BM=128,BN=64,BK=128, K=4096, z=4,
//               logical (16 m, 8 n, 4 z), XCD-chunk swizzled.
//   bid >= 512: lam_ment: BM=64,BN=64,BK=128, K=256, z=1 (2 kt iterations)
//               -> single lam slice, no split reduction needed.
// ---------------------------------------------------------------------------
__global__ __launch_bounds__(256) void gemm_all(
    const unsigned short* __restrict__ g_bf,
    const unsigned short* __restrict__ GAT,
    const unsigned short* __restrict__ mclip,
    const unsigned short* __restrict__ w_bf,
    unsigned short* __restrict__ mainp, unsigned short* __restrict__ lamp)
{
    __shared__ __align__(16) unsigned short Alds[128 * 128];
    __shared__ __align__(16) unsigned short Blds[64 * 128];
    const int bid = blockIdx.x;
    const int tid = threadIdx.x;
    const int lane = tid & 63, wid = tid >> 6;
    const int wr = wid >> 1, wc = wid & 1;

    if (bid < 512) {
        // ---- main path: logical (16 m, 8 n, 4 z), XCD-chunk swizzled ----
        const int l = (bid & 7) * 64 + (bid >> 3);
        const int m0 = (l & 15) * 128;
        const int n0 = ((l >> 4) & 7) * 64;
        const int z  = l >> 7;
        const int K = R_DIM, Kc = R_DIM / 4, k0 = z * Kc, NS = 512;
        unsigned short* part = mainp + (size_t)z * B_DIM * NS;
        f32x4 acc[4][2] = {};

        for (int kt = 0; kt < Kc; kt += 128) {
            const unsigned short* Ab = g_bf + (size_t)m0 * K + k0 + kt;
            const unsigned short* Bb = GAT  + (size_t)n0 * K + k0 + kt;
            #pragma unroll
            for (int q = 0; q < 8; q++) stage16(Alds, Ab, K, tid + q * 256);
            #pragma unroll
            for (int q = 0; q < 4; q++) stage16(Blds, Bb, K, tid + q * 256);
            __syncthreads();
            #pragma unroll
            for (int ks = 0; ks < 4; ks++) {
                const int k8 = ks * 4 + (lane >> 4);
                const int ra = wr * 64 + (lane & 15);
                const int rb = wc * 32 + (lane & 15);
                const int sa = (k8 ^ (ra & 15)) << 3;
                const int sb = (k8 ^ (rb & 15)) << 3;
                short8 a0 = *(const short8*)&Alds[(ra)      * 128 + sa];
                short8 a1 = *(const short8*)&Alds[(ra + 16) * 128 + sa];
                short8 a2 = *(const short8*)&Alds[(ra + 32) * 128 + sa];
                short8 a3 = *(const short8*)&Alds[(ra + 48) * 128 + sa];
                short8 b0 = *(const short8*)&Blds[(rb)      * 128 + sb];
                short8 b1 = *(const short8*)&Blds[(rb + 16) * 128 + sb];
                acc[0][0] = __builtin_amdgcn_mfma_f32_16x16x32_bf16(a0, b0, acc[0][0], 0, 0, 0);
                acc[0][1] = __builtin_amdgcn_mfma_f32_16x16x32_bf16(a0, b1, acc[0][1], 0, 0, 0);
                acc[1][0] = __builtin_amdgcn_mfma_f32_16x16x32_bf16(a1, b0, acc[1][0], 0, 0, 0);
                acc[1][1] = __builtin_amdgcn_mfma_f32_16x16x32_bf16(a1, b1, acc[1][1], 0, 0, 0);
                acc[2][0] = __builtin_amdgcn_mfma_f32_16x16x32_bf16(a2, b0, acc[2][0], 0, 0, 0);
                acc[2][1] = __builtin_amdgcn_mfma_f32_16x16x32_bf16(a2, b1, acc[2][1], 0, 0, 0);
                acc[3][0] = __builtin_amdgcn_mfma_f32_16x16x32_bf16(a3, b0, acc[3][0], 0, 0, 0);
                acc[3][1] = __builtin_amdgcn_mfma_f32_16x16x32_bf16(a3, b1, acc[3][1], 0, 0, 0);
            }
            __syncthreads();
        }
        const int rbase = (lane >> 4) * 4;
        const int cbase = lane & 15;
        #pragma unroll
        for (int i = 0; i < 4; i++) {
            #pragma unroll
            for (int j = 0; j < 2; j++) {
                const int gn = n0 + wc * 32 + j * 16 + cbase;
                #pragma unroll
                for (int q = 0; q < 4; q++) {
                    const int gm = m0 + wr * 64 + i * 16 + rbase + q;
                    part[(size_t)gm * NS + gn] = f2h(acc[i][j][q]);
                }
            }
        }
    } else {
        // ---- lam path: grid (32 m, 4 n), z=1, K=256 (2 kt iterations) ----
        const int l = bid - 512;
        const int m0 = (l & 31) * 64;
        const int n0 = (l >> 5) * 64;
        const int K = M_DIM, NS = A_DIM;
        f32x4 acc[2][2] = {};

        for (int kt = 0; kt < K; kt += 128) {
            const unsigned short* Ab = mclip + (size_t)m0 * K + kt;
            const unsigned short* Bb = w_bf  + (size_t)n0 * K + kt;
            #pragma unroll
            for (int q = 0; q < 4; q++) {
                stage16(Alds, Ab, K, tid + q * 256);
                stage16(Blds, Bb, K, tid + q * 256);
            }
            __syncthreads();
            #pragma unroll
            for (int ks = 0; ks < 4; ks++) {
                const int k8 = ks * 4 + (lane >> 4);
                const int r0a = wr * 32 + (lane & 15);
                const int r0b = wc * 32 + (lane & 15);
                const int sa = (k8 ^ (r0a & 15)) << 3;
                const int sb = (k8 ^ (r0b & 15)) << 3;
                short8 a0 = *(const short8*)&Alds[(r0a)      * 128 + sa];
                short8 a1 = *(const short8*)&Alds[(r0a + 16) * 128 + sa];
                short8 b0 = *(const short8*)&Blds[(r0b)      * 128 + sb];
                short8 b1 = *(const short8*)&Blds[(r0b + 16) * 128 + sb];
                acc[0][0] = __builtin_amdgcn_mfma_f32_16x16x32_bf16(a0, b0, acc[0][0], 0, 0, 0);
                acc[0][1] = __builtin_amdgcn_mfma_f32_16x16x32_bf16(a0, b1, acc[0][1], 0, 0, 0);
                acc[1][0] = __builtin_amdgcn_mfma_f32_16x16x32_bf16(a1, b0, acc[1][0], 0, 0, 0);
                acc[1][1] = __builtin_amdgcn_mfma_f32_16x16x32_bf16(a1, b1, acc[1][1], 0, 0, 0);
            }
            __syncthreads();
        }
        const int rbase = (lane >> 4) * 4;
        const int cbase = lane & 15;
        #pragma unroll
        for (int i = 0; i < 2; i++) {
            #pragma unroll
            for (int j = 0; j < 2; j++) {
                const int gn = n0 + wc * 32 + j * 16 + cbase;
                #pragma unroll
                for (int q = 0; q < 4; q++) {
                    const int gm = m0 + wr * 32 + i * 16 + rbase + q;
                    lamp[(size_t)gm * NS + gn] = f2h(acc[i][j][q]);
                }
            }
        }
    }
}

// ---------------------------------------------------------------------------
// Epilogue: sum f16 split-K main partials -> relu; lam cols +=
// softplus(b + lam[single slice]). float4-out over 2048x512.
// ---------------------------------------------------------------------------
__global__ __launch_bounds__(256) void epilogue(
    const unsigned short* __restrict__ mainpart,
    const unsigned short* __restrict__ lampart,
    const float* __restrict__ bvec, float* __restrict__ outp)
{
    const int idx = blockIdx.x * 256 + threadIdx.x;   // over 2048*128
    const int m = idx >> 7, n4 = idx & 127;
    const size_t mb = (size_t)m * 128 + n4;           // ushort4 units (NS=512)
    const size_t zs = (size_t)B_DIM * 128;
    float sx = 0.0f, sy = 0.0f, sz = 0.0f, sw = 0.0f;
    #pragma unroll
    for (int z = 0; z < 4; z++) {
        ushort4 t = ((const ushort4*)mainpart)[mb + z * zs];
        sx += h2f(t.x); sy += h2f(t.y); sz += h2f(t.z); sw += h2f(t.w);
    }
    sx = fmaxf(sx, 0.0f); sy = fmaxf(sy, 0.0f);
    sz = fmaxf(sz, 0.0f); sw = fmaxf(sw, 0.0f);
    if (n4 >= 64) {
        const int na = n4 - 64;                       // ushort4 idx in 256-col lam
        const size_t lb = (size_t)m * 64 + na;
        ushort4 u0 = ((const ushort4*)lampart)[lb];
        float4 bb = ((const float4*)bvec)[na];
        float x0 = bb.x + h2f(u0.x);
        float x1 = bb.y + h2f(u0.y);
        float x2 = bb.z + h2f(u0.z);
        float x3 = bb.w + h2f(u0.w);
        sx += (x0 > 20.0f) ? x0 : log1pf(__expf(x0));
        sy += (x1 > 20.0f) ? x1 : log1pf(__expf(x1));
        sz += (x2 > 20.0f) ? x2 : log1pf(__expf(x2));
        sw += (x3 > 20.0f) ? x3 : log1pf(__expf(x3));
    }
    float4 s; s.x = sx; s.y = sy; s.z = sz; s.w = sw;
    ((float4*)(outp + (size_t)m * OUT_STRIDE + 2048))[n4] = s;
}

// ---------------------------------------------------------------------------
extern "C" void kernel_launch(void* const* d_in, const int* in_sizes, int n_in,
                              void* d_out, int out_size, void* d_ws, size_t ws_size,
                              hipStream_t stream)
{
    const float* M_minus = (const float*)d_in[0];
    const float* amask   = (const float*)d_in[1];
    const float* gate    = (const float*)d_in[2];
    const float* bmask   = (const float*)d_in[3];
    const float* isM     = (const float*)d_in[4];
    const float* isA     = (const float*)d_in[5];
    const float* GA      = (const float*)d_in[6];
    const float* GB      = (const float*)d_in[7];
    const float* bvec    = (const float*)d_in[8];
    const float* w       = (const float*)d_in[9];
    const int*   bidx    = (const int*)d_in[10];
    const int*   hidx    = (const int*)d_in[11];
    float* outp = (float*)d_out;

    char* ws = (char*)d_ws;
    unsigned short* g_bf   = (unsigned short*)(ws + 0);          // 16 MiB
    unsigned short* GAT    = (unsigned short*)(ws + (16u<<20));  // 2 MiB
    unsigned short* GBT    = (unsigned short*)(ws + (18u<<20));  // 2 MiB (contiguous after GAT)
    unsigned short* w_bf   = (unsigned short*)(ws + (20u<<20));  // 128 KiB
    unsigned short* mclip  = (unsigned short*)(ws + (21u<<20));  // 1 MiB
    unsigned short* mainp  = (unsigned short*)(ws + (22u<<20));  // 4 x 2 MiB (f16)
    unsigned short* lamp   = (unsigned short*)(ws + (38u<<20));  // 1 MiB (f16)

    main_fused<<<dim3(B_DIM / NB), dim3(1024), 0, stream>>>(
        M_minus, amask, gate, bidx, bmask, hidx, GA, GB, isM, isA, w,
        GAT, GBT, w_bf, g_bf, mclip, outp);
    gemm_all<<<dim3(640), dim3(256), 0, stream>>>(
        g_bf, GAT, mclip, w_bf, mainp, lamp);
    epilogue<<<dim3((B_DIM * 128) / 256), dim3(256), 0, stream>>>(
        mainp, lamp, bvec, outp);
}